// Round 1
// baseline (6656.356 us; speedup 1.0000x reference)
//
#include <hip/hip_runtime.h>

typedef unsigned int u32;
typedef unsigned short u16;
typedef __attribute__((ext_vector_type(2))) _Float16 h2v;
typedef __attribute__((ext_vector_type(4))) _Float16 f16x4;
typedef __attribute__((ext_vector_type(4))) float f32x4;

#define BB 32
#define TT 2048
#define CC 256
#define ESZ 256
#define GG 1024   // 4*es

// ---------------- helpers ----------------
__device__ __forceinline__ float fdot2u(u32 a, u32 b, float c) {
#if __has_builtin(__builtin_amdgcn_fdot2)
  return __builtin_amdgcn_fdot2(__builtin_bit_cast(h2v, a), __builtin_bit_cast(h2v, b), c, false);
#else
  h2v av = __builtin_bit_cast(h2v, a), bv = __builtin_bit_cast(h2v, b);
  return c + (float)av[0] * (float)bv[0] + (float)av[1] * (float)bv[1];
#endif
}

__device__ __forceinline__ float sigm_f(float x) {
  float e = __builtin_amdgcn_exp2f(x * -1.442695041f);
  return __builtin_amdgcn_rcpf(1.0f + e);
}
__device__ __forceinline__ float tanh_f(float x) {
  float e = __builtin_amdgcn_exp2f(x * 2.885390082f);  // exp(2x)
  return 1.0f - 2.0f * __builtin_amdgcn_rcpf(e + 1.0f);
}

// ---------------- kernel 0: pack W2 (f32 [256][1024] -> f16-pair [128][1024]) ----------------
__global__ void k_pack_w2(const float* __restrict__ W2, u32* __restrict__ W2p) {
  int gid = blockIdx.x * 256 + threadIdx.x;   // 0..131071 ; m = gid>>10, j = gid&1023
  int m = gid >> 10, j = gid & 1023;
  _Float16 lo = (_Float16)W2[(size_t)(2 * m) * GG + j];
  _Float16 hi = (_Float16)W2[(size_t)(2 * m + 1) * GG + j];
  W2p[gid] = (u32)__builtin_bit_cast(u16, lo) | ((u32)__builtin_bit_cast(u16, hi) << 16);
}

// ---------------- kernel 1: pre = x@W1 + b1 + b2  (f16 MFMA, out f16 [B*T][1024]) ----------------
__global__ __launch_bounds__(256, 2) void k_pre_gemm(
    const float* __restrict__ x, const float* __restrict__ W1,
    const float* __restrict__ b1, const float* __restrict__ b2,
    _Float16* __restrict__ pre) {
  // tile: BM=128, BN=64, BK=32 ; 4 waves in 2x2; per wave 64x32 = 4x2 frags of 16x16
  __shared__ __attribute__((aligned(16))) _Float16 Al[128 * 36];  // [row][k] pad 36
  __shared__ __attribute__((aligned(16))) _Float16 Bl[64 * 36];   // [col][k] (transposed) pad 36
  const int tid = threadIdx.x;
  const int lane = tid & 63, wv = tid >> 6;
  const int wr = wv >> 1, wc = wv & 1;
  const int rowBase = blockIdx.x * 128;
  const int colBase = blockIdx.y * 64;

  f32x4 acc[4][2];
#pragma unroll
  for (int mi = 0; mi < 4; ++mi)
#pragma unroll
    for (int ni = 0; ni < 2; ++ni) acc[mi][ni] = (f32x4){0.f, 0.f, 0.f, 0.f};

  for (int k0 = 0; k0 < 256; k0 += 32) {
    // stage A: 128 rows x 32 k (f32 -> f16)
#pragma unroll
    for (int i = 0; i < 4; ++i) {
      int fidx = tid + 256 * i;              // 0..1023 float4s
      int row = fidx >> 3, kc = (fidx & 7) * 4;
      const float4 v = *(const float4*)(x + (size_t)(rowBase + row) * 256 + k0 + kc);
      f16x4 hv = { (_Float16)v.x, (_Float16)v.y, (_Float16)v.z, (_Float16)v.w };
      *(f16x4*)&Al[row * 36 + kc] = hv;
    }
    // stage B transposed: W1[k0+k][colBase+n] -> Bl[n][k]
#pragma unroll
    for (int i = 0; i < 8; ++i) {
      int idx = tid + 256 * i;               // 0..2047
      int k = idx >> 6, n = idx & 63;
      Bl[n * 36 + k] = (_Float16)W1[(size_t)(k0 + k) * GG + colBase + n];
    }
    __syncthreads();

#pragma unroll
    for (int kk = 0; kk < 2; ++kk) {
      int ka = (lane >> 4) * 4 + kk * 16;
      f16x4 af[4], bf[2];
#pragma unroll
      for (int mi = 0; mi < 4; ++mi)
        af[mi] = *(const f16x4*)&Al[(wr * 64 + mi * 16 + (lane & 15)) * 36 + ka];
#pragma unroll
      for (int ni = 0; ni < 2; ++ni)
        bf[ni] = *(const f16x4*)&Bl[(wc * 32 + ni * 16 + (lane & 15)) * 36 + ka];
#pragma unroll
      for (int mi = 0; mi < 4; ++mi)
#pragma unroll
        for (int ni = 0; ni < 2; ++ni)
          acc[mi][ni] = __builtin_amdgcn_mfma_f32_16x16x16f16(af[mi], bf[ni], acc[mi][ni], 0, 0, 0);
    }
    __syncthreads();
  }

  // epilogue: add bias, store f16
#pragma unroll
  for (int ni = 0; ni < 2; ++ni) {
    int col = colBase + wc * 32 + ni * 16 + (lane & 15);
    float bias = b1[col] + b2[col];
#pragma unroll
    for (int mi = 0; mi < 4; ++mi) {
      int r0 = rowBase + wr * 64 + mi * 16 + (lane >> 4) * 4;
#pragma unroll
      for (int rr = 0; rr < 4; ++rr)
        pre[(size_t)(r0 + rr) * GG + col] = (_Float16)(acc[mi][ni][rr] + bias);
    }
  }
}

// ---------------- kernel 2: the recurrence ----------------
// 32 blocks (one per batch), 256 threads. Thread t owns gate columns {t, t+256, t+512, t+768}.
// W2 resident: m=0..107 in VGPRs (4x108 packed half2), m=108..127 in LDS (80KB).
// h double-buffered in LDS as f16; c in registers. One barrier per step.
#define MREG 108   // half2 rows in registers
#define QREG 27    // MREG/4
#define QLDS 5     // (128-MREG)/4 chunks in LDS

__global__ __launch_bounds__(256, 1) void k_lstm_rec(
    const _Float16* __restrict__ pre, const u32* __restrict__ W2p,
    const float* __restrict__ h0, const float* __restrict__ c0,
    float* __restrict__ out1, float* __restrict__ out2,
    float* __restrict__ hN, float* __restrict__ cN) {
  extern __shared__ __attribute__((aligned(16))) char smem[];
  uint4* W2L4w = (uint4*)smem;                         // QLDS*1024 uint4 = 80KB
  const uint4* W2L4 = (const uint4*)smem;
  _Float16* hbh = (_Float16*)(smem + QLDS * 1024 * 16);     // 2 x 256 f16 = 1KB
  const uint4* hb4 = (const uint4*)(smem + QLDS * 1024 * 16);

  const int t = threadIdx.x;
  const int b = blockIdx.x;

  // load register-resident W2 columns (packed half2 along k)
  u32 w0[MREG], w1[MREG], w2r[MREG], w3[MREG];
#pragma unroll
  for (int m = 0; m < MREG; ++m) {
    w0[m]  = W2p[m * GG + t];
    w1[m]  = W2p[m * GG + t + 256];
    w2r[m] = W2p[m * GG + t + 512];
    w3[m]  = W2p[m * GG + t + 768];
  }
  // stage LDS-resident part of W2: rows m=MREG..127, layout [chunk][col][4 half2]
  for (int idx = t; idx < QLDS * 1024; idx += 256) {
    int qq = idx >> 10, j = idx & 1023;
    int m0 = MREG + 4 * qq;
    uint4 v;
    v.x = W2p[(m0 + 0) * GG + j];
    v.y = W2p[(m0 + 1) * GG + j];
    v.z = W2p[(m0 + 2) * GG + j];
    v.w = W2p[(m0 + 3) * GG + j];
    W2L4w[idx] = v;
  }
  // init h buffer 0 and c register
  hbh[t] = (_Float16)h0[b * ESZ + t];
  float creg = c0[b * ESZ + t];
  __syncthreads();

  const _Float16* preB = pre + (size_t)b * TT * GG;
  const size_t o1base = (size_t)b * TT * ESZ + t;
  float hlast = 0.f;

  _Float16 q0 = preB[t], q1 = preB[t + 256], q2 = preB[t + 512], q3 = preB[t + 768];

  for (int s = 0; s < TT; ++s) {
    float acc0 = (float)q0, acc1 = (float)q1, acc2 = (float)q2, acc3 = (float)q3;
    if (s + 1 < TT) {  // prefetch next step's pre (hides HBM latency under the dot)
      const _Float16* pn = preB + (size_t)(s + 1) * GG;
      q0 = pn[t]; q1 = pn[t + 256]; q2 = pn[t + 512]; q3 = pn[t + 768];
    }
    const int curBase = (s & 1) * 32;

#pragma unroll
    for (int q = 0; q < 32; ++q) {
      uint4 hh = hb4[curBase + q];             // broadcast read: h[8q..8q+7] as 4 half2
      u32 hx[4] = {hh.x, hh.y, hh.z, hh.w};
      if (q < QREG) {
#pragma unroll
        for (int r = 0; r < 4; ++r) {
          acc0 = fdot2u(hx[r], w0[4 * q + r], acc0);
          acc1 = fdot2u(hx[r], w1[4 * q + r], acc1);
          acc2 = fdot2u(hx[r], w2r[4 * q + r], acc2);
          acc3 = fdot2u(hx[r], w3[4 * q + r], acc3);
        }
      } else {
        const int qi = (q - QREG) * 1024;
        uint4 wa = W2L4[qi + t];
        uint4 wb = W2L4[qi + t + 256];
        uint4 wcv = W2L4[qi + t + 512];
        uint4 wd = W2L4[qi + t + 768];
        u32 wax[4] = {wa.x, wa.y, wa.z, wa.w};
        u32 wbx[4] = {wb.x, wb.y, wb.z, wb.w};
        u32 wcx[4] = {wcv.x, wcv.y, wcv.z, wcv.w};
        u32 wdx[4] = {wd.x, wd.y, wd.z, wd.w};
#pragma unroll
        for (int r = 0; r < 4; ++r) {
          acc0 = fdot2u(hx[r], wax[r], acc0);
          acc1 = fdot2u(hx[r], wbx[r], acc1);
          acc2 = fdot2u(hx[r], wcx[r], acc2);
          acc3 = fdot2u(hx[r], wdx[r], acc3);
        }
      }
    }

    float fg = sigm_f(acc0);
    float ig = sigm_f(acc1);
    float og = sigm_f(acc2);
    float ch = tanh_f(acc3);
    creg = fg * creg + ig * ch;
    float hv = og * tanh_f(creg);
    hlast = hv;

    out1[o1base + (size_t)s * ESZ] = hv;                       // [B, T*es]
    out2[(size_t)s * (BB * ESZ) + b * ESZ + t] = hv;           // [T, B, es]
    hbh[((s & 1) ^ 1) * 256 + t] = (_Float16)hv;               // next step's h
    __syncthreads();
  }

  hN[b * ESZ + t] = hlast;
  cN[b * ESZ + t] = creg;
}

// ---------------- launch ----------------
extern "C" void kernel_launch(void* const* d_in, const int* in_sizes, int n_in,
                              void* d_out, int out_size, void* d_ws, size_t ws_size,
                              hipStream_t stream) {
  const float* x  = (const float*)d_in[0];
  const float* h0 = (const float*)d_in[1];
  const float* c0 = (const float*)d_in[2];
  const float* W1 = (const float*)d_in[3];
  const float* W2 = (const float*)d_in[4];
  const float* b1 = (const float*)d_in[5];
  const float* b2 = (const float*)d_in[6];

  float* out1 = (float*)d_out;
  float* out2 = out1 + (size_t)BB * TT * ESZ;
  float* hN   = out2 + (size_t)BB * TT * ESZ;
  float* cN   = hN + BB * ESZ;

  _Float16* pre = (_Float16*)d_ws;                                  // 128 MB
  u32* W2p = (u32*)((char*)d_ws + (size_t)BB * TT * GG * 2);        // 512 KB

  k_pack_w2<<<512, 256, 0, stream>>>(W2, W2p);
  k_pre_gemm<<<dim3(512, 16), 256, 0, stream>>>(x, W1, b1, b2, pre);

  const int ldsBytes = QLDS * 1024 * 16 + 1024;  // 80KB W2 tail + 2x256 f16 h buffers
  hipFuncSetAttribute((const void*)k_lstm_rec, hipFuncAttributeMaxDynamicSharedMemorySize, ldsBytes);
  k_lstm_rec<<<BB, 256, ldsBytes, stream>>>(pre, W2p, h0, c0, out1, out2, hN, cN);
}

// Round 2
// 3736.608 us; speedup vs baseline: 1.7814x; 1.7814x over previous
//
#include <hip/hip_runtime.h>

typedef unsigned int u32;
typedef unsigned short u16;
typedef __attribute__((ext_vector_type(2))) _Float16 h2v;
typedef __attribute__((ext_vector_type(4))) _Float16 f16x4;
typedef __attribute__((ext_vector_type(4))) float f32x4;

#define BB 32
#define TT 2048
#define CC 256
#define ESZ 256
#define GG 1024   // 4*es

#define RREG 100  // half2 rows of W2 per column kept in VGPRs
#define NCH 7     // (128-RREG)/4 uint4 chunks per column in LDS

// ---------------- helpers ----------------
__device__ __forceinline__ float fdot2u(u32 a, u32 b, float c) {
#if __has_builtin(__builtin_amdgcn_fdot2)
  return __builtin_amdgcn_fdot2(__builtin_bit_cast(h2v, a), __builtin_bit_cast(h2v, b), c, false);
#else
  h2v av = __builtin_bit_cast(h2v, a), bv = __builtin_bit_cast(h2v, b);
  return c + (float)av[0] * (float)bv[0] + (float)av[1] * (float)bv[1];
#endif
}

__device__ __forceinline__ float sigm_f(float x) {
  float e = __builtin_amdgcn_exp2f(x * -1.442695041f);
  return __builtin_amdgcn_rcpf(1.0f + e);
}
__device__ __forceinline__ float tanh_f(float x) {
  float e = __builtin_amdgcn_exp2f(x * 2.885390082f);  // exp(2x)
  return 1.0f - 2.0f * __builtin_amdgcn_rcpf(e + 1.0f);
}

// ---------------- kernel 0: pack W2 (f32 [256][1024] -> f16-pair [128][1024]) ----------------
__global__ void k_pack_w2(const float* __restrict__ W2, u32* __restrict__ W2p) {
  int gid = blockIdx.x * 256 + threadIdx.x;   // 0..131071 ; m = gid>>10, j = gid&1023
  int m = gid >> 10, j = gid & 1023;
  _Float16 lo = (_Float16)W2[(size_t)(2 * m) * GG + j];
  _Float16 hi = (_Float16)W2[(size_t)(2 * m + 1) * GG + j];
  W2p[gid] = (u32)__builtin_bit_cast(u16, lo) | ((u32)__builtin_bit_cast(u16, hi) << 16);
}

// ---------------- kernel 1: pre = x@W1 + b1 + b2  (f16 MFMA, out f16 [B*T][1024]) ----------------
__global__ __launch_bounds__(256, 2) void k_pre_gemm(
    const float* __restrict__ x, const float* __restrict__ W1,
    const float* __restrict__ b1, const float* __restrict__ b2,
    _Float16* __restrict__ pre) {
  __shared__ __attribute__((aligned(16))) _Float16 Al[128 * 36];
  __shared__ __attribute__((aligned(16))) _Float16 Bl[64 * 36];
  const int tid = threadIdx.x;
  const int lane = tid & 63, wv = tid >> 6;
  const int wr = wv >> 1, wc = wv & 1;
  const int rowBase = blockIdx.x * 128;
  const int colBase = blockIdx.y * 64;

  f32x4 acc[4][2];
#pragma unroll
  for (int mi = 0; mi < 4; ++mi)
#pragma unroll
    for (int ni = 0; ni < 2; ++ni) acc[mi][ni] = (f32x4){0.f, 0.f, 0.f, 0.f};

  for (int k0 = 0; k0 < 256; k0 += 32) {
#pragma unroll
    for (int i = 0; i < 4; ++i) {
      int fidx = tid + 256 * i;
      int row = fidx >> 3, kc = (fidx & 7) * 4;
      const float4 v = *(const float4*)(x + (size_t)(rowBase + row) * 256 + k0 + kc);
      f16x4 hv = { (_Float16)v.x, (_Float16)v.y, (_Float16)v.z, (_Float16)v.w };
      *(f16x4*)&Al[row * 36 + kc] = hv;
    }
#pragma unroll
    for (int i = 0; i < 8; ++i) {
      int idx = tid + 256 * i;
      int k = idx >> 6, n = idx & 63;
      Bl[n * 36 + k] = (_Float16)W1[(size_t)(k0 + k) * GG + colBase + n];
    }
    __syncthreads();

#pragma unroll
    for (int kk = 0; kk < 2; ++kk) {
      int ka = (lane >> 4) * 4 + kk * 16;
      f16x4 af[4], bf[2];
#pragma unroll
      for (int mi = 0; mi < 4; ++mi)
        af[mi] = *(const f16x4*)&Al[(wr * 64 + mi * 16 + (lane & 15)) * 36 + ka];
#pragma unroll
      for (int ni = 0; ni < 2; ++ni)
        bf[ni] = *(const f16x4*)&Bl[(wc * 32 + ni * 16 + (lane & 15)) * 36 + ka];
#pragma unroll
      for (int mi = 0; mi < 4; ++mi)
#pragma unroll
        for (int ni = 0; ni < 2; ++ni)
          acc[mi][ni] = __builtin_amdgcn_mfma_f32_16x16x16f16(af[mi], bf[ni], acc[mi][ni], 0, 0, 0);
    }
    __syncthreads();
  }

#pragma unroll
  for (int ni = 0; ni < 2; ++ni) {
    int col = colBase + wc * 32 + ni * 16 + (lane & 15);
    float bias = b1[col] + b2[col];
#pragma unroll
    for (int mi = 0; mi < 4; ++mi) {
      int r0 = rowBase + wr * 64 + mi * 16 + (lane >> 4) * 4;
#pragma unroll
      for (int rr = 0; rr < 4; ++rr)
        pre[(size_t)(r0 + rr) * GG + col] = (_Float16)(acc[mi][ni][rr] + bias);
    }
  }
}

// ---------------- kernel 2: the recurrence ----------------
// 32 blocks (one per batch), 512 threads (8 waves, 2/SIMD).
// Thread t: j = t&255, half = t>>8. half0 owns gate cols (f: j, i: j+256),
// half1 owns (o: j+512, ch: j+768). W2: rows 0..RREG-1 per column in VGPRs
// (2*RREG regs/thread), rows RREG..127 in LDS (NCH uint4 chunks/column).
// h replicated via 2 per-lane ds_read_b32 + v_readlane -> SGPR feeding v_dot2.
__global__ __launch_bounds__(512, 2) void k_lstm_rec(
    const _Float16* __restrict__ pre, const u32* __restrict__ W2p,
    const float* __restrict__ h0, const float* __restrict__ c0,
    float* __restrict__ out1, float* __restrict__ out2,
    float* __restrict__ hN, float* __restrict__ cN) {
  extern __shared__ __attribute__((aligned(16))) char smem[];
  uint4* W2Lw = (uint4*)smem;                                   // NCH*1024 uint4 = 112 KB
  const uint4* W2L = (const uint4*)smem;
  _Float16* hbuf = (_Float16*)(smem + NCH * 1024 * 16);         // 256 f16 = 512 B
  const u32* hrow = (const u32*)(smem + NCH * 1024 * 16);       // h as 128 half2
  float2* exch = (float2*)(smem + NCH * 1024 * 16 + 512);       // 256 float2 = 2 KB

  const int t = threadIdx.x;
  const int b = blockIdx.x;
  const int j = t & 255, half = t >> 8;
  const int lane = t & 63;
  const int col0 = j + half * 512;      // f (half0) / o (half1)
  const int col1 = col0 + 256;          // i (half0) / ch (half1)

  // register-resident W2 rows
  u32 wA[RREG], wB[RREG];
#pragma unroll
  for (int m = 0; m < RREG; ++m) {
    wA[m] = W2p[m * GG + col0];
    wB[m] = W2p[m * GG + col1];
  }
  // LDS-resident W2 rows: chunk c covers rows RREG+4c .. RREG+4c+3
  for (int idx = t; idx < NCH * 1024; idx += 512) {
    int cch = idx >> 10, col = idx & 1023;
    int m0 = RREG + 4 * cch;
    uint4 v;
    v.x = W2p[(m0 + 0) * GG + col];
    v.y = W2p[(m0 + 1) * GG + col];
    v.z = W2p[(m0 + 2) * GG + col];
    v.w = W2p[(m0 + 3) * GG + col];
    W2Lw[idx] = v;
  }

  float creg = 0.f, hlast = 0.f;
  if (!half) {
    hbuf[j] = (_Float16)h0[b * ESZ + j];
    creg = c0[b * ESZ + j];
  }
  __syncthreads();

  const _Float16* preB = pre + (size_t)b * TT * GG;
  const size_t o1base = (size_t)b * TT * ESZ + j;

  _Float16 q0 = preB[col0], q1 = preB[col1];

  for (int s = 0; s < TT; ++s) {
    // per-lane h load (conflict-free b32), replicate via readlane below
    u32 hv0 = hrow[lane];
    u32 hv1 = hrow[64 + lane];

    float a0 = (float)q0, a1 = (float)q1;
    if (s + 1 < TT) {
      const _Float16* pn = preB + (size_t)(s + 1) * GG;
      q0 = pn[col0];
      q1 = pn[col1];
    }
    float p0 = 0.f, p1 = 0.f;  // second accumulator pair (ILP)

#pragma unroll
    for (int m = 0; m < 64; ++m) {
      u32 hm = (u32)__builtin_amdgcn_readlane((int)hv0, m);
      a0 = fdot2u(hm, wA[m], a0);
      a1 = fdot2u(hm, wB[m], a1);
    }
#pragma unroll
    for (int m = 0; m < RREG - 64; ++m) {
      u32 hm = (u32)__builtin_amdgcn_readlane((int)hv1, m);
      p0 = fdot2u(hm, wA[64 + m], p0);
      p1 = fdot2u(hm, wB[64 + m], p1);
    }
#pragma unroll
    for (int cch = 0; cch < NCH; ++cch) {
      uint4 wa = W2L[cch * 1024 + col0];
      uint4 wb = W2L[cch * 1024 + col1];
      u32 h0m = (u32)__builtin_amdgcn_readlane((int)hv1, RREG - 64 + 4 * cch + 0);
      u32 h1m = (u32)__builtin_amdgcn_readlane((int)hv1, RREG - 64 + 4 * cch + 1);
      u32 h2m = (u32)__builtin_amdgcn_readlane((int)hv1, RREG - 64 + 4 * cch + 2);
      u32 h3m = (u32)__builtin_amdgcn_readlane((int)hv1, RREG - 64 + 4 * cch + 3);
      p0 = fdot2u(h0m, wa.x, p0); p1 = fdot2u(h0m, wb.x, p1);
      p0 = fdot2u(h1m, wa.y, p0); p1 = fdot2u(h1m, wb.y, p1);
      p0 = fdot2u(h2m, wa.z, p0); p1 = fdot2u(h2m, wb.z, p1);
      p0 = fdot2u(h3m, wa.w, p0); p1 = fdot2u(h3m, wb.w, p1);
    }
    a0 += p0;
    a1 += p1;

    float fg = 0.f, ig = 0.f;
    if (half) {
      exch[j] = make_float2(sigm_f(a0), tanh_f(a1));  // (o_gate, c_hat)
    } else {
      fg = sigm_f(a0);
      ig = sigm_f(a1);
    }
    __syncthreads();  // barrier1: exch ready; all h reads of this step done

    if (!half) {
      float2 e = exch[j];
      creg = fg * creg + ig * e.y;
      float hv = e.x * tanh_f(creg);
      hlast = hv;
      out1[o1base + (size_t)s * ESZ] = hv;                 // [B, T*es]
      out2[(size_t)s * (BB * ESZ) + b * ESZ + j] = hv;     // [T, B, es]
      hbuf[j] = (_Float16)hv;
    }
    __syncthreads();  // barrier2: next step's h visible
  }

  if (!half) {
    hN[b * ESZ + j] = hlast;
    cN[b * ESZ + j] = creg;
  }
}

// ---------------- launch ----------------
extern "C" void kernel_launch(void* const* d_in, const int* in_sizes, int n_in,
                              void* d_out, int out_size, void* d_ws, size_t ws_size,
                              hipStream_t stream) {
  const float* x  = (const float*)d_in[0];
  const float* h0 = (const float*)d_in[1];
  const float* c0 = (const float*)d_in[2];
  const float* W1 = (const float*)d_in[3];
  const float* W2 = (const float*)d_in[4];
  const float* b1 = (const float*)d_in[5];
  const float* b2 = (const float*)d_in[6];

  float* out1 = (float*)d_out;
  float* out2 = out1 + (size_t)BB * TT * ESZ;
  float* hN   = out2 + (size_t)BB * TT * ESZ;
  float* cN   = hN + BB * ESZ;

  _Float16* pre = (_Float16*)d_ws;                                  // 128 MB
  u32* W2p = (u32*)((char*)d_ws + (size_t)BB * TT * GG * 2);        // 512 KB

  k_pack_w2<<<512, 256, 0, stream>>>(W2, W2p);
  k_pre_gemm<<<dim3(512, 16), 256, 0, stream>>>(x, W1, b1, b2, pre);

  const int ldsBytes = NCH * 1024 * 16 + 512 + 2048;  // W2 tail + hbuf + exch
  hipFuncSetAttribute((const void*)k_lstm_rec, hipFuncAttributeMaxDynamicSharedMemorySize, ldsBytes);
  k_lstm_rec<<<BB, 512, ldsBytes, stream>>>(pre, W2p, h0, c0, out1, out2, hN, cN);
}